// Round 11
// baseline (325.743 us; speedup 1.0000x reference)
//
#include <hip/hip_runtime.h>

#define N_NODES 80000
#define N_EDGES 64000
#define NB      32
#define NG      2500
#define NA      50
#define EDIM    16
#define FIN     159      // H2(64) + AF(95)
#define HG      128
#define NBANKS  21       // RI2 banks: 18 root(t,k) + 3 init(k), each [1600][128]

typedef __attribute__((ext_vector_type(8))) short bf16x8;
typedef __attribute__((ext_vector_type(4))) float f32x4;

__device__ inline ushort rne_bf16(float f) {
    union { float f; unsigned u; } v; v.f = f;
    const unsigned r = v.u + 0x7fffu + ((v.u >> 16) & 1u);
    return (ushort)(r >> 16);
}
__device__ inline float bf16_to_f32(ushort h) {
    union { unsigned u; float f; } v; v.u = ((unsigned)h) << 16;
    return v.f;
}
__device__ __forceinline__ void gl_lds16(const void* gsrc, void* ldst) {
    __builtin_amdgcn_global_load_lds(
        (const __attribute__((address_space(1))) unsigned int*)gsrc,
        (__attribute__((address_space(3))) unsigned int*)ldst, 16, 0, 0);
}

// ---------------- merged weight prep: conv fragments + arma fragments ----------------
__global__ __launch_bounds__(256) void prep_all(const float* __restrict__ we1, const float* __restrict__ be1,
    const float* __restrict__ we2, const float* __restrict__ be2, const float* __restrict__ armaw,
    ushort* __restrict__ w1h, ushort* __restrict__ w1l, ushort* __restrict__ w2h, ushort* __restrict__ w2l,
    ushort* __restrict__ abh, ushort* __restrict__ abl)
{
    const int b = blockIdx.x;
    if (b < 68) {
        int idx = b * 256 + threadIdx.x;
        const int half = (idx >= 17 * 8 * 64) ? 1 : 0;
        if (half) idx -= 17 * 8 * 64;
        if (idx >= 17 * 8 * 64) return;
        const float* we = half ? we2 : we1;
        const float* be = half ? be2 : be1;
        ushort* Wh = half ? w2h : w1h;
        ushort* Wlo = half ? w2l : w1l;
        const int l = idx & 63;
        const int slot = (idx >> 6) & 7;
        const int j = idx >> 9;
        const int n = slot >> 1, kq = slot & 1;
        const int o = n * 16 + (l & 15);
        const int i0 = kq * 32 + (l >> 4) * 8;
        ushort th[8], tl[8];
#pragma unroll
        for (int t = 0; t < 8; ++t) {
            const int i = i0 + t;
            const float f = (j < 16) ? we[j * 4096 + i * 64 + o] : be[i * 64 + o];
            const ushort hi = rne_bf16(f);
            th[t] = hi;
            tl[t] = rne_bf16(f - bf16_to_f32(hi));
        }
        *(uint4*)(Wh + (size_t)idx * 8) = *(const uint4*)th;
        *(uint4*)(Wlo + (size_t)idx * 8) = *(const uint4*)tl;
    } else {
        const int idx = (b - 68) * 256 + threadIdx.x;
        if (idx >= 15 * 32 * 64) return;
        const int l = idx & 63;
        const int slot = (idx >> 6) & 31;
        const int ws = idx >> 11;
        const int n = slot >> 2, kt = slot & 3;
        const int c = n * 16 + (l & 15);
        const int f0 = kt * 32 + (l >> 4) * 8;
        ushort th[8], tl[8];
#pragma unroll
        for (int t = 0; t < 8; ++t) {
            const float v = armaw[(size_t)ws * 16384 + (size_t)(f0 + t) * 128 + c];
            const ushort hi = rne_bf16(v);
            th[t] = hi;
            tl[t] = rne_bf16(v - bf16_to_f32(hi));
        }
        *(uint4*)(abh + (size_t)idx * 8) = *(const uint4*)th;
        *(uint4*)(abl + (size_t)idx * 8) = *(const uint4*)tl;
    }
}

// ---------------- root GEMM: out[n,:] = relu?(in[n,:]) @ W(64x64) + bias ----------------
template<int RELU>
__global__ __launch_bounds__(256) void root_gemm(const float* __restrict__ in,
    const float* __restrict__ w, const float* __restrict__ bias, float* __restrict__ out)
{
    __shared__ float At[64 * 65];
    __shared__ float Wl[64 * 64];
    __shared__ float bl[64];
    const int tid = threadIdx.x;
    const int r0 = blockIdx.x * 64;
    for (int s = tid; s < 4096; s += 256) {
        int r = s >> 6, c = s & 63;
        float v = in[(r0 + r) * 64 + c];
        if (RELU) v = fmaxf(v, 0.f);
        At[c * 65 + r] = v;
    }
    for (int s = tid; s < 4096; s += 256) Wl[s] = w[s];
    if (tid < 64) bl[tid] = bias[tid];
    __syncthreads();
    const int tr = tid >> 4, tc = tid & 15;
    float acc[4][4] = {};
#pragma unroll 8
    for (int i = 0; i < 64; ++i) {
        const float4 a4 = *(const float4*)&At[i * 65 + tr * 4];
        const float4 b4 = *(const float4*)&Wl[i * 64 + tc * 4];
        const float av[4] = {a4.x, a4.y, a4.z, a4.w};
        const float bv[4] = {b4.x, b4.y, b4.z, b4.w};
#pragma unroll
        for (int m = 0; m < 4; ++m)
#pragma unroll
            for (int n = 0; n < 4; ++n) acc[m][n] = fmaf(av[m], bv[n], acc[m][n]);
    }
    const float4 bq = *(const float4*)&bl[tc * 4];
#pragma unroll
    for (int m = 0; m < 4; ++m) {
        float4 o4 = {acc[m][0] + bq.x, acc[m][1] + bq.y, acc[m][2] + bq.z, acc[m][3] + bq.w};
        *(float4*)&out[(r0 + tr * 4 + m) * 64 + tc * 4] = o4;
    }
}

// ---------------- NNConv edge kernel v4: 4 waves = (edge-half) x (output-half) ----------------
// Each wave: 64 edges (m=4 tiles of 16) x 32 outputs (n=2 tiles of 16).
// Per j: 8 LDS B-reads feed 48 MFMA (3x reuse vs v3). B staged in LDS via gl_lds dbuf.
#define TE 128
template<int RELU>
__global__ __launch_bounds__(256) void edge_conv_mfma(const float* __restrict__ h,
    const float* __restrict__ ea, const int* __restrict__ src, const int* __restrict__ dst,
    const ushort* __restrict__ Whi, const ushort* __restrict__ Wlo, float* __restrict__ agg)
{
    __shared__ ushort Bst[2][8192];     // per buf 16KB: hi chunks [0..8), lo chunks [8..16) of 1KB
    __shared__ float  EAt[17 * 132];
    const int tid = threadIdx.x;
    const int e0 = blockIdx.x * TE;
    const int wv = tid >> 6, l = tid & 63;
    const int we = wv >> 1;             // edge half: rows we*64..we*64+63
    const int wn = wv & 1;              // output half: n in {wn*2, wn*2+1}

    // async prefetch B(j=0): 16 chunks, wave covers 4
#pragma unroll
    for (int i = 0; i < 4; ++i) {
        const int c = wv * 4 + i;
        const ushort* gs = (c < 8) ? (Whi + ((size_t)c * 64 + l) * 8)
                                   : (Wlo + ((size_t)(c - 8) * 64 + l) * 8);
        gl_lds16(gs, (char*)(&Bst[0][0]) + c * 1024);
    }
    for (int s = tid; s < TE * 16; s += 256) {
        const int le = s >> 4, j = s & 15;
        EAt[j * 132 + le] = ea[(size_t)(e0 + le) * 16 + j];
    }
    if (tid < TE) EAt[16 * 132 + tid] = 1.0f;

    // A fragments: 4 row-tiles (64 edges), hi/lo, per-lane gather from h
    bf16x8 ah[4][2], al[4][2];
#pragma unroll
    for (int mt = 0; mt < 4; ++mt) {
        const int erow = we * 64 + mt * 16 + (l & 15);
        const int nd = src[e0 + erow];
        const float4* hp = (const float4*)(h + (size_t)nd * 64);
#pragma unroll
        for (int kq = 0; kq < 2; ++kq) {
            const int q0 = kq * 8 + (l >> 4) * 2;
            const float4 v0 = hp[q0], v1 = hp[q0 + 1];
            const float fv[8] = {v0.x, v0.y, v0.z, v0.w, v1.x, v1.y, v1.z, v1.w};
            ushort th[8], tl[8];
#pragma unroll
            for (int t = 0; t < 8; ++t) {
                const float f = RELU ? fmaxf(fv[t], 0.f) : fv[t];
                th[t] = rne_bf16(f);
                tl[t] = rne_bf16(f - bf16_to_f32(th[t]));
            }
            ah[mt][kq] = *(const bf16x8*)th;
            al[mt][kq] = *(const bf16x8*)tl;
        }
    }
    __syncthreads();   // drains B(0) + EA

    f32x4 msg[4][2];
#pragma unroll
    for (int mt = 0; mt < 4; ++mt)
#pragma unroll
        for (int n2 = 0; n2 < 2; ++n2) msg[mt][n2] = (f32x4)0.f;

#pragma unroll 1
    for (int j = 0; j < 17; ++j) {
        const int cur = j & 1;
        if (j < 16) {
#pragma unroll
            for (int i = 0; i < 4; ++i) {
                const int c = wv * 4 + i;
                const ushort* gs = (c < 8) ? (Whi + ((size_t)((j + 1) * 8 + c) * 64 + l) * 8)
                                           : (Wlo + ((size_t)((j + 1) * 8 + (c - 8)) * 64 + l) * 8);
                gl_lds16(gs, (char*)(&Bst[cur ^ 1][0]) + c * 1024);
            }
        }
        f32x4 eam[4];
#pragma unroll
        for (int mt = 0; mt < 4; ++mt)
            eam[mt] = *(const f32x4*)&EAt[j * 132 + we * 64 + mt * 16 + (l >> 4) * 4];
#pragma unroll
        for (int n2 = 0; n2 < 2; ++n2) {
            const int n = wn * 2 + n2;
            const char* bb = (const char*)(&Bst[cur][0]);
            const bf16x8 bh0 = *(const bf16x8*)(bb + ((n * 2 + 0) * 64 + l) * 16);
            const bf16x8 bh1 = *(const bf16x8*)(bb + ((n * 2 + 1) * 64 + l) * 16);
            const bf16x8 bl0 = *(const bf16x8*)(bb + 8192 + ((n * 2 + 0) * 64 + l) * 16);
            const bf16x8 bl1 = *(const bf16x8*)(bb + 8192 + ((n * 2 + 1) * 64 + l) * 16);
#pragma unroll
            for (int mt = 0; mt < 4; ++mt) {
                f32x4 t = __builtin_amdgcn_mfma_f32_16x16x32_bf16(ah[mt][0], bh0, (f32x4)0.f, 0, 0, 0);
                t = __builtin_amdgcn_mfma_f32_16x16x32_bf16(ah[mt][1], bh1, t, 0, 0, 0);
                t = __builtin_amdgcn_mfma_f32_16x16x32_bf16(ah[mt][0], bl0, t, 0, 0, 0);
                t = __builtin_amdgcn_mfma_f32_16x16x32_bf16(ah[mt][1], bl1, t, 0, 0, 0);
                t = __builtin_amdgcn_mfma_f32_16x16x32_bf16(al[mt][0], bh0, t, 0, 0, 0);
                t = __builtin_amdgcn_mfma_f32_16x16x32_bf16(al[mt][1], bh1, t, 0, 0, 0);
                msg[mt][n2] += eam[mt] * t;
            }
        }
        __syncthreads();
    }

    // direct atomic scatter: col = n*16+(l&15), row = (l>>4)*4+r within tile
#pragma unroll
    for (int mt = 0; mt < 4; ++mt)
#pragma unroll
        for (int r = 0; r < 4; ++r) {
            const int erow = we * 64 + mt * 16 + (l >> 4) * 4 + r;
            const size_t d = (size_t)dst[e0 + erow] * 64;
#pragma unroll
            for (int n2 = 0; n2 < 2; ++n2) {
                const int col = (wn * 2 + n2) * 16 + (l & 15);
                atomicAdd(&agg[d + col], msg[mt][n2][r]);
            }
        }
}

// ---------------- atom attention scores (relu on load) ----------------
__global__ __launch_bounds__(256) void scores_k(const float* __restrict__ h2,
    const float* __restrict__ w, const float* __restrict__ b, float* __restrict__ sc)
{
    __shared__ float wl[64];
    if (threadIdx.x < 64) wl[threadIdx.x] = w[threadIdx.x];
    __syncthreads();
    const int n = blockIdx.x * 256 + threadIdx.x;
    if (n < N_NODES) {
        float acc = b[0];
        const float4* hp = (const float4*)(h2 + (long)n * 64);
#pragma unroll
        for (int q = 0; q < 16; ++q) {
            const float4 v = hp[q];
            acc = fmaf(fmaxf(v.x, 0.f), wl[q * 4 + 0], acc); acc = fmaf(fmaxf(v.y, 0.f), wl[q * 4 + 1], acc);
            acc = fmaf(fmaxf(v.z, 0.f), wl[q * 4 + 2], acc); acc = fmaf(fmaxf(v.w, 0.f), wl[q * 4 + 3], acc);
        }
        sc[n] = acc;
    }
}

// ---------------- per-graph softmax over atoms ----------------
__global__ __launch_bounds__(256) void softmax_k(const float* __restrict__ sc, float* __restrict__ attn)
{
    __shared__ float red[256];
    const int g = blockIdx.x, tid = threadIdx.x;
    const float* s = sc + (long)g * NG;
    float m = -1e30f;
    for (int a = tid; a < NG; a += 256) m = fmaxf(m, s[a]);
    red[tid] = m; __syncthreads();
    for (int st = 128; st; st >>= 1) { if (tid < st) red[tid] = fmaxf(red[tid], red[tid + st]); __syncthreads(); }
    const float mx = red[0]; __syncthreads();
    float sum = 0.f;
    for (int a = tid; a < NG; a += 256) sum += expf(s[a] - mx);
    red[tid] = sum; __syncthreads();
    for (int st = 128; st; st >>= 1) { if (tid < st) red[tid] += red[tid + st]; __syncthreads(); }
    const float inv = 1.0f / red[0];
    for (int a = tid; a < NG; a += 256) attn[(long)g * NG + a] = expf(s[a] - mx) * inv;
}

// ---------------- residue pooling + xi concat (relu on load) ----------------
__global__ __launch_bounds__(256) void amino_k(const float* __restrict__ h2,
    const float* __restrict__ attn, const float* __restrict__ aa, float* __restrict__ xi)
{
    const int tid = threadIdx.x;
    const int r = blockIdx.x * 4 + (tid >> 6);
    const int o = tid & 63;
    const int g = r / NA, ar = r % NA;
    const long base = (long)g * NG + ar * 50;
    float acc = 0.f;
#pragma unroll 10
    for (int a = 0; a < 50; ++a) acc = fmaf(attn[base + a], fmaxf(h2[(base + a) * 64 + o], 0.f), acc);
    xi[(long)r * FIN + o] = acc;
    for (int s = tid; s < 4 * 95; s += 256) {
        const int lr = s / 95, f = s % 95;
        const int rr = blockIdx.x * 4 + lr;
        xi[(long)rr * FIN + 64 + f] = aa[(long)rr * 95 + f];
    }
}

// ---------------- RI GEMM -> bank-major RI2[bank][1600][128] ----------------
__global__ __launch_bounds__(256) void ri_gemm(const float* __restrict__ xi,
    const float* __restrict__ rootw, const float* __restrict__ initw,
    const float* __restrict__ abias, float* __restrict__ RI2)
{
    __shared__ float At[32 * 65];
    __shared__ float Bl[32 * 64];
    const int tid = threadIdx.x;
    const int r0 = blockIdx.x * 64, c0 = blockIdx.y * 64;
    const int blk = c0 >> 7;
    const int gb = c0 & 127;
    const float* bsrc = (blk < 18) ? (rootw + (long)blk * FIN * 128) : (initw + (long)(blk - 18) * FIN * 128);
    const int tr = tid >> 4, tc = tid & 15;
    float acc[4][4] = {};
    for (int f0 = 0; f0 < FIN; f0 += 32) {
        __syncthreads();
        for (int s = tid; s < 64 * 32; s += 256) {
            const int r = s >> 5, kk = s & 31; const int f = f0 + kk;
            At[kk * 65 + r] = (f < FIN) ? xi[(long)(r0 + r) * FIN + f] : 0.f;
        }
        for (int s = tid; s < 32 * 64; s += 256) {
            const int kk = s >> 6, cc = s & 63; const int f = f0 + kk;
            Bl[s] = (f < FIN) ? bsrc[(long)f * 128 + gb + cc] : 0.f;
        }
        __syncthreads();
#pragma unroll 8
        for (int kk = 0; kk < 32; ++kk) {
            const float4 a4 = *(const float4*)&At[kk * 65 + tr * 4];
            const float4 b4 = *(const float4*)&Bl[kk * 64 + tc * 4];
            const float av[4] = {a4.x, a4.y, a4.z, a4.w};
            const float bv[4] = {b4.x, b4.y, b4.z, b4.w};
#pragma unroll
            for (int m = 0; m < 4; ++m)
#pragma unroll
                for (int n = 0; n < 4; ++n) acc[m][n] = fmaf(av[m], bv[n], acc[m][n]);
        }
    }
    float4 bq = {0.f, 0.f, 0.f, 0.f};
    if (blk < 18) bq = *(const float4*)&abias[c0 + tc * 4];
#pragma unroll
    for (int m = 0; m < 4; ++m) {
        float4 o4 = {acc[m][0] + bq.x, acc[m][1] + bq.y, acc[m][2] + bq.z, acc[m][3] + bq.w};
        *(float4*)&RI2[((size_t)blk * 1600 + (r0 + tr * 4 + m)) * 128 + gb + tc * 4] = o4;
    }
}

// ---------------- ARMA per-step MFMA: 1200 single-wave blocks, 16 rows x 32 cols each ----------------
template<int INIT>
__global__ __launch_bounds__(64) void arma_step_mfma(const float* __restrict__ Xin,
    const float* __restrict__ RI2, const ushort* __restrict__ Bh, const ushort* __restrict__ Bl,
    float* __restrict__ Xout, int t)
{
    const int rt = blockIdx.x, cg = blockIdx.y, k = blockIdx.z;
    const int l = threadIdx.x;
    const int r0 = rt * 16;

    const int ar = r0 + (l & 15);
    const int aa = ar % NA;
    const bool avalid = (aa >= 2);
    const int asrc = avalid ? (ar - 1) : ar;
    bf16x8 ah[4], al[4];
#pragma unroll
    for (int kt = 0; kt < 4; ++kt) {
        const int coff = kt * 32 + (l >> 4) * 8;
        float fv[8];
        if (INIT) {
            const float4 u0 = *(const float4*)(RI2 + ((size_t)k * 1600 + asrc) * 128 + coff);
            const float4 u1 = *(const float4*)(RI2 + ((size_t)k * 1600 + asrc) * 128 + coff + 4);
            const int psrc = (asrc >= 1) ? (asrc - 1) : 0;
            const float4 p0 = *(const float4*)(RI2 + ((size_t)(18 + k) * 1600 + psrc) * 128 + coff);
            const float4 p1 = *(const float4*)(RI2 + ((size_t)(18 + k) * 1600 + psrc) * 128 + coff + 4);
            const float pm = (aa >= 3) ? 1.f : 0.f;
            fv[0] = fmaxf(u0.x + pm * p0.x, 0.f); fv[1] = fmaxf(u0.y + pm * p0.y, 0.f);
            fv[2] = fmaxf(u0.z + pm * p0.z, 0.f); fv[3] = fmaxf(u0.w + pm * p0.w, 0.f);
            fv[4] = fmaxf(u1.x + pm * p1.x, 0.f); fv[5] = fmaxf(u1.y + pm * p1.y, 0.f);
            fv[6] = fmaxf(u1.z + pm * p1.z, 0.f); fv[7] = fmaxf(u1.w + pm * p1.w, 0.f);
        } else {
            const float4 u0 = *(const float4*)(Xin + ((size_t)k * 1600 + asrc) * 128 + coff);
            const float4 u1 = *(const float4*)(Xin + ((size_t)k * 1600 + asrc) * 128 + coff + 4);
            fv[0] = u0.x; fv[1] = u0.y; fv[2] = u0.z; fv[3] = u0.w;
            fv[4] = u1.x; fv[5] = u1.y; fv[6] = u1.z; fv[7] = u1.w;
        }
        ushort th[8], tl[8];
#pragma unroll
        for (int t8 = 0; t8 < 8; ++t8) {
            const float f = avalid ? fv[t8] : 0.f;
            th[t8] = rne_bf16(f);
            tl[t8] = rne_bf16(f - bf16_to_f32(th[t8]));
        }
        ah[kt] = *(const bf16x8*)th;
        al[kt] = *(const bf16x8*)tl;
    }

    f32x4 acc[2];
    acc[0] = (f32x4)0.f; acc[1] = (f32x4)0.f;
    const size_t wb = (size_t)(((t - 1) * 3 + k) * 32) * 512;
#pragma unroll
    for (int kt = 0; kt < 4; ++kt) {
        bf16x8 bh2[2], bl2[2];
#pragma unroll
        for (int n2 = 0; n2 < 2; ++n2) {
            const int n = cg * 2 + n2;
            const size_t fo = wb + (size_t)(n * 4 + kt) * 512 + (size_t)l * 8;
            bh2[n2] = *(const bf16x8*)(Bh + fo);
            bl2[n2] = *(const bf16x8*)(Bl + fo);
        }
#pragma unroll
        for (int n2 = 0; n2 < 2; ++n2) {
            acc[n2] = __builtin_amdgcn_mfma_f32_16x16x32_bf16(ah[kt], bh2[n2], acc[n2], 0, 0, 0);
            acc[n2] = __builtin_amdgcn_mfma_f32_16x16x32_bf16(ah[kt], bl2[n2], acc[n2], 0, 0, 0);
            acc[n2] = __builtin_amdgcn_mfma_f32_16x16x32_bf16(al[kt], bh2[n2], acc[n2], 0, 0, 0);
        }
    }

    const float* rroot = RI2 + (size_t)(t * 3 + k) * 1600 * 128;
#pragma unroll
    for (int n2 = 0; n2 < 2; ++n2) {
        const int col = (cg * 2 + n2) * 16 + (l & 15);
#pragma unroll
        for (int r = 0; r < 4; ++r) {
            const int crow = r0 + (l >> 4) * 4 + r;
            const float rv = rroot[(size_t)crow * 128 + col];
            Xout[((size_t)k * 1600 + crow) * 128 + col] = fmaxf(acc[n2][r] + rv, 0.f);
        }
    }
}

// ---------------- final: mean over k-banks + relu, aa-attention, MLP ----------------
__global__ __launch_bounds__(256) void final_k(const float* __restrict__ G,
    const float* __restrict__ waa, const float* __restrict__ baa,
    const float* __restrict__ w1, const float* __restrict__ b1,
    const float* __restrict__ w2, const float* __restrict__ b2,
    const float* __restrict__ w3, const float* __restrict__ b3,
    const float* __restrict__ w4, const float* __restrict__ b4, float* __restrict__ out)
{
    __shared__ float gl[50 * 129];
    __shared__ float sc[64];
    __shared__ float pl[128];
    __shared__ float h1l[64], h2l[32], h3l[16];
    __shared__ float wl[128];
    const int b = blockIdx.x, tid = threadIdx.x;
    for (int s = tid; s < 50 * 128; s += 256) {
        const int a = s >> 7, o = s & 127;
        const size_t r = ((size_t)b * 50 + a) * 128 + o;
        const float v = (G[r] + G[(size_t)1600 * 128 + r] + G[(size_t)2 * 1600 * 128 + r]) * (1.f / 3.f);
        gl[a * 129 + o] = fmaxf(v, 0.f);
    }
    if (tid < 128) wl[tid] = waa[tid];
    __syncthreads();
    if (tid < 50) {
        float acc = baa[0];
        for (int f = 0; f < 128; ++f) acc = fmaf(gl[tid * 129 + f], wl[f], acc);
        sc[tid] = acc;
    }
    __syncthreads();
    if (tid < 64) {
        const float v = (tid < 50) ? sc[tid] : -1e30f;
        float m = v;
        for (int d = 32; d; d >>= 1) m = fmaxf(m, __shfl_xor(m, d));
        const float e = (tid < 50) ? expf(v - m) : 0.f;
        float ssum = e;
        for (int d = 32; d; d >>= 1) ssum += __shfl_xor(ssum, d);
        if (tid < 50) sc[tid] = e / ssum;
    }
    __syncthreads();
    if (tid < 128) {
        float acc = 0.f;
        for (int a = 0; a < 50; ++a) acc = fmaf(sc[a], gl[a * 129 + tid], acc);
        pl[tid] = acc;
    }
    __syncthreads();
    if (tid < 64) {
        float acc = b1[tid];
        for (int f = 0; f < 128; ++f) acc = fmaf(pl[f], w1[f * 64 + tid], acc);
        h1l[tid] = fmaxf(acc, 0.f);
    }
    __syncthreads();
    if (tid < 32) {
        float acc = b2[tid];
        for (int f = 0; f < 64; ++f) acc = fmaf(h1l[f], w2[f * 32 + tid], acc);
        h2l[tid] = fmaxf(acc, 0.f);
    }
    __syncthreads();
    if (tid < 16) {
        float acc = b3[tid];
        for (int f = 0; f < 32; ++f) acc = fmaf(h2l[f], w3[f * 16 + tid], acc);
        h3l[tid] = fmaxf(acc, 0.f);
    }
    __syncthreads();
    if (tid == 0) {
        float acc = b4[0];
        for (int f = 0; f < 16; ++f) acc = fmaf(h3l[f], w4[f], acc);
        out[b] = acc;
    }
}

extern "C" void kernel_launch(void* const* d_in, const int* in_sizes, int n_in,
                              void* d_out, int out_size, void* d_ws, size_t ws_size,
                              hipStream_t stream) {
    const float* x     = (const float*)d_in[0];
    const int*   eidx  = (const int*)d_in[1];
    const float* ea    = (const float*)d_in[2];
    const float* aaf   = (const float*)d_in[4];
    const float* we1   = (const float*)d_in[5];
    const float* be1   = (const float*)d_in[6];
    const float* root1 = (const float*)d_in[7];
    const float* bias1 = (const float*)d_in[8];
    const float* we2   = (const float*)d_in[9];
    const float* be2   = (const float*)d_in[10];
    const float* root2 = (const float*)d_in[11];
    const float* bias2 = (const float*)d_in[12];
    const float* waw   = (const float*)d_in[13];
    const float* wab   = (const float*)d_in[14];
    const float* initw = (const float*)d_in[15];
    const float* armaw = (const float*)d_in[16];
    const float* rootw = (const float*)d_in[17];
    const float* abias = (const float*)d_in[18];
    const float* waa   = (const float*)d_in[19];
    const float* baa   = (const float*)d_in[20];
    const float* w1    = (const float*)d_in[21];
    const float* b1    = (const float*)d_in[22];
    const float* w2    = (const float*)d_in[23];
    const float* b2    = (const float*)d_in[24];
    const float* w3    = (const float*)d_in[25];
    const float* b3    = (const float*)d_in[26];
    const float* w4    = (const float*)d_in[27];
    const float* b4    = (const float*)d_in[28];
    float* out = (float*)d_out;

    const int* src = eidx;
    const int* dst = eidx + N_EDGES;

    char* ws = (char*)d_ws;
    size_t off = 0;
    float* h1     = (float*)(ws + off); off += (size_t)N_NODES * 64 * 4;
    float* h2     = (float*)(ws + off); off += (size_t)N_NODES * 64 * 4;
    float* scores = (float*)(ws + off); off += (size_t)N_NODES * 4;
    float* attn   = (float*)(ws + off); off += (size_t)N_NODES * 4;
    float* xi     = (float*)(ws + off); off += (size_t)1600 * FIN * 4;
    float* RI2    = (float*)(ws + off); off += (size_t)NBANKS * 1600 * 128 * 4;
    float* XA     = (float*)(ws + off); off += (size_t)3 * 1600 * 128 * 4;
    float* XB     = (float*)(ws + off); off += (size_t)3 * 1600 * 128 * 4;
    float* G      = (float*)(ws + off); off += (size_t)3 * 1600 * 128 * 4;
    ushort* wt1h  = (ushort*)(ws + off); off += (size_t)17 * 8 * 64 * 8 * 2;
    ushort* wt1l  = (ushort*)(ws + off); off += (size_t)17 * 8 * 64 * 8 * 2;
    ushort* wt2h  = (ushort*)(ws + off); off += (size_t)17 * 8 * 64 * 8 * 2;
    ushort* wt2l  = (ushort*)(ws + off); off += (size_t)17 * 8 * 64 * 8 * 2;
    ushort* abh   = (ushort*)(ws + off); off += (size_t)15 * 32 * 64 * 8 * 2;
    ushort* abl   = (ushort*)(ws + off); off += (size_t)15 * 32 * 64 * 8 * 2;

    prep_all<<<188, 256, 0, stream>>>(we1, be1, we2, be2, armaw, wt1h, wt1l, wt2h, wt2l, abh, abl);

    // conv1 (relu deferred to consumers)
    root_gemm<0><<<N_NODES / 64, 256, 0, stream>>>(x, root1, bias1, h1);
    edge_conv_mfma<0><<<N_EDGES / TE, 256, 0, stream>>>(x, ea, src, dst, wt1h, wt1l, h1);
    // conv2 (reads relu(h1) on load)
    root_gemm<1><<<N_NODES / 64, 256, 0, stream>>>(h1, root2, bias2, h2);
    edge_conv_mfma<1><<<N_EDGES / TE, 256, 0, stream>>>(h1, ea, src, dst, wt2h, wt2l, h2);
    // attention pooling -> xi
    scores_k<<<(N_NODES + 255) / 256, 256, 0, stream>>>(h2, waw, wab, scores);
    softmax_k<<<NB, 256, 0, stream>>>(scores, attn);
    amino_k<<<1600 / 4, 256, 0, stream>>>(h2, attn, aaf, xi);
    // ARMA: RI2 banks, then 5 wide per-step dispatches (t=5 writes G)
    ri_gemm<<<dim3(25, 42), 256, 0, stream>>>(xi, rootw, initw, abias, RI2);
    const dim3 agrid(100, 4, 3);
    arma_step_mfma<1><<<agrid, 64, 0, stream>>>(XB, RI2, abh, abl, XA, 1);
    arma_step_mfma<0><<<agrid, 64, 0, stream>>>(XA, RI2, abh, abl, XB, 2);
    arma_step_mfma<0><<<agrid, 64, 0, stream>>>(XB, RI2, abh, abl, XA, 3);
    arma_step_mfma<0><<<agrid, 64, 0, stream>>>(XA, RI2, abh, abl, XB, 4);
    arma_step_mfma<0><<<agrid, 64, 0, stream>>>(XB, RI2, abh, abl, G, 5);
    // readout + MLP
    final_k<<<NB, 256, 0, stream>>>(G, waa, baa, w1, b1, w2, b2, w3, b3, w4, b4, out);
}

// Round 12
// 318.725 us; speedup vs baseline: 1.0220x; 1.0220x over previous
//
#include <hip/hip_runtime.h>

#define N_NODES 80000
#define N_EDGES 64000
#define NB      32
#define NG      2500
#define NA      50
#define EDIM    16
#define FIN     159      // H2(64) + AF(95)
#define HG      128
#define NBANKS  21       // RI2 banks: 18 root(t,k) + 3 init(k), each [1600][128]

typedef __attribute__((ext_vector_type(8))) short bf16x8;
typedef __attribute__((ext_vector_type(4))) float f32x4;

__device__ inline ushort rne_bf16(float f) {
    union { float f; unsigned u; } v; v.f = f;
    const unsigned r = v.u + 0x7fffu + ((v.u >> 16) & 1u);
    return (ushort)(r >> 16);
}
__device__ inline float bf16_to_f32(ushort h) {
    union { unsigned u; float f; } v; v.u = ((unsigned)h) << 16;
    return v.f;
}
__device__ __forceinline__ void gl_lds16(const void* gsrc, void* ldst) {
    __builtin_amdgcn_global_load_lds(
        (const __attribute__((address_space(1))) unsigned int*)gsrc,
        (__attribute__((address_space(3))) unsigned int*)ldst, 16, 0, 0);
}

// ---------------- merged weight prep: conv fragments + arma fragments ----------------
__global__ __launch_bounds__(256) void prep_all(const float* __restrict__ we1, const float* __restrict__ be1,
    const float* __restrict__ we2, const float* __restrict__ be2, const float* __restrict__ armaw,
    ushort* __restrict__ w1h, ushort* __restrict__ w1l, ushort* __restrict__ w2h, ushort* __restrict__ w2l,
    ushort* __restrict__ abh, ushort* __restrict__ abl)
{
    const int b = blockIdx.x;
    if (b < 68) {
        int idx = b * 256 + threadIdx.x;
        const int half = (idx >= 17 * 8 * 64) ? 1 : 0;
        if (half) idx -= 17 * 8 * 64;
        if (idx >= 17 * 8 * 64) return;
        const float* we = half ? we2 : we1;
        const float* be = half ? be2 : be1;
        ushort* Wh = half ? w2h : w1h;
        ushort* Wlo = half ? w2l : w1l;
        const int l = idx & 63;
        const int slot = (idx >> 6) & 7;
        const int j = idx >> 9;
        const int n = slot >> 1, kq = slot & 1;
        const int o = n * 16 + (l & 15);
        const int i0 = kq * 32 + (l >> 4) * 8;
        ushort th[8], tl[8];
#pragma unroll
        for (int t = 0; t < 8; ++t) {
            const int i = i0 + t;
            const float f = (j < 16) ? we[j * 4096 + i * 64 + o] : be[i * 64 + o];
            const ushort hi = rne_bf16(f);
            th[t] = hi;
            tl[t] = rne_bf16(f - bf16_to_f32(hi));
        }
        *(uint4*)(Wh + (size_t)idx * 8) = *(const uint4*)th;
        *(uint4*)(Wlo + (size_t)idx * 8) = *(const uint4*)tl;
    } else {
        const int idx = (b - 68) * 256 + threadIdx.x;
        if (idx >= 15 * 32 * 64) return;
        const int l = idx & 63;
        const int slot = (idx >> 6) & 31;
        const int ws = idx >> 11;
        const int n = slot >> 2, kt = slot & 3;
        const int c = n * 16 + (l & 15);
        const int f0 = kt * 32 + (l >> 4) * 8;
        ushort th[8], tl[8];
#pragma unroll
        for (int t = 0; t < 8; ++t) {
            const float v = armaw[(size_t)ws * 16384 + (size_t)(f0 + t) * 128 + c];
            const ushort hi = rne_bf16(v);
            th[t] = hi;
            tl[t] = rne_bf16(v - bf16_to_f32(hi));
        }
        *(uint4*)(abh + (size_t)idx * 8) = *(const uint4*)th;
        *(uint4*)(abl + (size_t)idx * 8) = *(const uint4*)tl;
    }
}

// ---------------- root GEMM: out[n,:] = relu?(in[n,:]) @ W(64x64) + bias ----------------
template<int RELU>
__global__ __launch_bounds__(256) void root_gemm(const float* __restrict__ in,
    const float* __restrict__ w, const float* __restrict__ bias, float* __restrict__ out)
{
    __shared__ float At[64 * 65];
    __shared__ float Wl[64 * 64];
    __shared__ float bl[64];
    const int tid = threadIdx.x;
    const int r0 = blockIdx.x * 64;
    for (int s = tid; s < 4096; s += 256) {
        int r = s >> 6, c = s & 63;
        float v = in[(r0 + r) * 64 + c];
        if (RELU) v = fmaxf(v, 0.f);
        At[c * 65 + r] = v;
    }
    for (int s = tid; s < 4096; s += 256) Wl[s] = w[s];
    if (tid < 64) bl[tid] = bias[tid];
    __syncthreads();
    const int tr = tid >> 4, tc = tid & 15;
    float acc[4][4] = {};
#pragma unroll 8
    for (int i = 0; i < 64; ++i) {
        const float4 a4 = *(const float4*)&At[i * 65 + tr * 4];
        const float4 b4 = *(const float4*)&Wl[i * 64 + tc * 4];
        const float av[4] = {a4.x, a4.y, a4.z, a4.w};
        const float bv[4] = {b4.x, b4.y, b4.z, b4.w};
#pragma unroll
        for (int m = 0; m < 4; ++m)
#pragma unroll
            for (int n = 0; n < 4; ++n) acc[m][n] = fmaf(av[m], bv[n], acc[m][n]);
    }
    const float4 bq = *(const float4*)&bl[tc * 4];
#pragma unroll
    for (int m = 0; m < 4; ++m) {
        float4 o4 = {acc[m][0] + bq.x, acc[m][1] + bq.y, acc[m][2] + bq.z, acc[m][3] + bq.w};
        *(float4*)&out[(r0 + tr * 4 + m) * 64 + tc * 4] = o4;
    }
}

// ---------------- NNConv edge kernel v5: TE=64, 4 waves = (edge-half 32) x (out-half 32) ----------------
// grid 1000 blocks, ~37 KB LDS -> 4 blocks/CU resident (16 waves/CU).
// Per wave per j: 8 LDS B-reads feed 24 MFMA. B staged per-block via gl_lds dbuf.
#define TE 64
template<int RELU>
__global__ __launch_bounds__(256) void edge_conv_mfma(const float* __restrict__ h,
    const float* __restrict__ ea, const int* __restrict__ src, const int* __restrict__ dst,
    const ushort* __restrict__ Whi, const ushort* __restrict__ Wlo, float* __restrict__ agg)
{
    __shared__ ushort Bst[2][8192];     // per buf 16KB: hi chunks [0..8), lo chunks [8..16) of 1KB
    __shared__ float  EAt[17 * 68];     // [j][edge]
    const int tid = threadIdx.x;
    const int e0 = blockIdx.x * TE;
    const int wv = tid >> 6, l = tid & 63;
    const int we = wv >> 1;             // edge half: rows we*32..we*32+31
    const int wn = wv & 1;              // output half: n in {wn*2, wn*2+1}

    // async prefetch B(j=0): 16 chunks, wave covers 4
#pragma unroll
    for (int i = 0; i < 4; ++i) {
        const int c = wv * 4 + i;
        const ushort* gs = (c < 8) ? (Whi + ((size_t)c * 64 + l) * 8)
                                   : (Wlo + ((size_t)(c - 8) * 64 + l) * 8);
        gl_lds16(gs, (char*)(&Bst[0][0]) + c * 1024);
    }
    for (int s = tid; s < TE * 16; s += 256) {
        const int le = s >> 4, j = s & 15;
        EAt[j * 68 + le] = ea[(size_t)(e0 + le) * 16 + j];
    }
    if (tid < TE) EAt[16 * 68 + tid] = 1.0f;

    // A fragments: 2 row-tiles (32 edges), hi/lo, per-lane gather from h
    bf16x8 ah[2][2], al[2][2];
#pragma unroll
    for (int mt = 0; mt < 2; ++mt) {
        const int erow = we * 32 + mt * 16 + (l & 15);
        const int nd = src[e0 + erow];
        const float4* hp = (const float4*)(h + (size_t)nd * 64);
#pragma unroll
        for (int kq = 0; kq < 2; ++kq) {
            const int q0 = kq * 8 + (l >> 4) * 2;
            const float4 v0 = hp[q0], v1 = hp[q0 + 1];
            const float fv[8] = {v0.x, v0.y, v0.z, v0.w, v1.x, v1.y, v1.z, v1.w};
            ushort th[8], tl[8];
#pragma unroll
            for (int t = 0; t < 8; ++t) {
                const float f = RELU ? fmaxf(fv[t], 0.f) : fv[t];
                th[t] = rne_bf16(f);
                tl[t] = rne_bf16(f - bf16_to_f32(th[t]));
            }
            ah[mt][kq] = *(const bf16x8*)th;
            al[mt][kq] = *(const bf16x8*)tl;
        }
    }
    __syncthreads();   // drains B(0) + EA

    f32x4 msg[2][2];
#pragma unroll
    for (int mt = 0; mt < 2; ++mt)
#pragma unroll
        for (int n2 = 0; n2 < 2; ++n2) msg[mt][n2] = (f32x4)0.f;

#pragma unroll 1
    for (int j = 0; j < 17; ++j) {
        const int cur = j & 1;
        if (j < 16) {
#pragma unroll
            for (int i = 0; i < 4; ++i) {
                const int c = wv * 4 + i;
                const ushort* gs = (c < 8) ? (Whi + ((size_t)((j + 1) * 8 + c) * 64 + l) * 8)
                                           : (Wlo + ((size_t)((j + 1) * 8 + (c - 8)) * 64 + l) * 8);
                gl_lds16(gs, (char*)(&Bst[cur ^ 1][0]) + c * 1024);
            }
        }
        f32x4 eam[2];
#pragma unroll
        for (int mt = 0; mt < 2; ++mt)
            eam[mt] = *(const f32x4*)&EAt[j * 68 + we * 32 + mt * 16 + (l >> 4) * 4];
#pragma unroll
        for (int n2 = 0; n2 < 2; ++n2) {
            const int n = wn * 2 + n2;
            const char* bb = (const char*)(&Bst[cur][0]);
            const bf16x8 bh0 = *(const bf16x8*)(bb + ((n * 2 + 0) * 64 + l) * 16);
            const bf16x8 bh1 = *(const bf16x8*)(bb + ((n * 2 + 1) * 64 + l) * 16);
            const bf16x8 bl0 = *(const bf16x8*)(bb + 8192 + ((n * 2 + 0) * 64 + l) * 16);
            const bf16x8 bl1 = *(const bf16x8*)(bb + 8192 + ((n * 2 + 1) * 64 + l) * 16);
#pragma unroll
            for (int mt = 0; mt < 2; ++mt) {
                f32x4 t = __builtin_amdgcn_mfma_f32_16x16x32_bf16(ah[mt][0], bh0, (f32x4)0.f, 0, 0, 0);
                t = __builtin_amdgcn_mfma_f32_16x16x32_bf16(ah[mt][1], bh1, t, 0, 0, 0);
                t = __builtin_amdgcn_mfma_f32_16x16x32_bf16(ah[mt][0], bl0, t, 0, 0, 0);
                t = __builtin_amdgcn_mfma_f32_16x16x32_bf16(ah[mt][1], bl1, t, 0, 0, 0);
                t = __builtin_amdgcn_mfma_f32_16x16x32_bf16(al[mt][0], bh0, t, 0, 0, 0);
                t = __builtin_amdgcn_mfma_f32_16x16x32_bf16(al[mt][1], bh1, t, 0, 0, 0);
                msg[mt][n2] += eam[mt] * t;
            }
        }
        __syncthreads();
    }

    // direct atomic scatter: col = n*16+(l&15), row = (l>>4)*4+r within tile
#pragma unroll
    for (int mt = 0; mt < 2; ++mt)
#pragma unroll
        for (int r = 0; r < 4; ++r) {
            const int erow = we * 32 + mt * 16 + (l >> 4) * 4 + r;
            const size_t d = (size_t)dst[e0 + erow] * 64;
#pragma unroll
            for (int n2 = 0; n2 < 2; ++n2) {
                const int col = (wn * 2 + n2) * 16 + (l & 15);
                atomicAdd(&agg[d + col], msg[mt][n2][r]);
            }
        }
}

// ---------------- atom attention scores (relu on load) ----------------
__global__ __launch_bounds__(256) void scores_k(const float* __restrict__ h2,
    const float* __restrict__ w, const float* __restrict__ b, float* __restrict__ sc)
{
    __shared__ float wl[64];
    if (threadIdx.x < 64) wl[threadIdx.x] = w[threadIdx.x];
    __syncthreads();
    const int n = blockIdx.x * 256 + threadIdx.x;
    if (n < N_NODES) {
        float acc = b[0];
        const float4* hp = (const float4*)(h2 + (long)n * 64);
#pragma unroll
        for (int q = 0; q < 16; ++q) {
            const float4 v = hp[q];
            acc = fmaf(fmaxf(v.x, 0.f), wl[q * 4 + 0], acc); acc = fmaf(fmaxf(v.y, 0.f), wl[q * 4 + 1], acc);
            acc = fmaf(fmaxf(v.z, 0.f), wl[q * 4 + 2], acc); acc = fmaf(fmaxf(v.w, 0.f), wl[q * 4 + 3], acc);
        }
        sc[n] = acc;
    }
}

// ---------------- per-graph softmax over atoms ----------------
__global__ __launch_bounds__(256) void softmax_k(const float* __restrict__ sc, float* __restrict__ attn)
{
    __shared__ float red[256];
    const int g = blockIdx.x, tid = threadIdx.x;
    const float* s = sc + (long)g * NG;
    float m = -1e30f;
    for (int a = tid; a < NG; a += 256) m = fmaxf(m, s[a]);
    red[tid] = m; __syncthreads();
    for (int st = 128; st; st >>= 1) { if (tid < st) red[tid] = fmaxf(red[tid], red[tid + st]); __syncthreads(); }
    const float mx = red[0]; __syncthreads();
    float sum = 0.f;
    for (int a = tid; a < NG; a += 256) sum += expf(s[a] - mx);
    red[tid] = sum; __syncthreads();
    for (int st = 128; st; st >>= 1) { if (tid < st) red[tid] += red[tid + st]; __syncthreads(); }
    const float inv = 1.0f / red[0];
    for (int a = tid; a < NG; a += 256) attn[(long)g * NG + a] = expf(s[a] - mx) * inv;
}

// ---------------- residue pooling + xi concat (relu on load) ----------------
__global__ __launch_bounds__(256) void amino_k(const float* __restrict__ h2,
    const float* __restrict__ attn, const float* __restrict__ aa, float* __restrict__ xi)
{
    const int tid = threadIdx.x;
    const int r = blockIdx.x * 4 + (tid >> 6);
    const int o = tid & 63;
    const int g = r / NA, ar = r % NA;
    const long base = (long)g * NG + ar * 50;
    float acc = 0.f;
#pragma unroll 10
    for (int a = 0; a < 50; ++a) acc = fmaf(attn[base + a], fmaxf(h2[(base + a) * 64 + o], 0.f), acc);
    xi[(long)r * FIN + o] = acc;
    for (int s = tid; s < 4 * 95; s += 256) {
        const int lr = s / 95, f = s % 95;
        const int rr = blockIdx.x * 4 + lr;
        xi[(long)rr * FIN + 64 + f] = aa[(long)rr * 95 + f];
    }
}

// ---------------- RI GEMM -> bank-major RI2[bank][1600][128] ----------------
__global__ __launch_bounds__(256) void ri_gemm(const float* __restrict__ xi,
    const float* __restrict__ rootw, const float* __restrict__ initw,
    const float* __restrict__ abias, float* __restrict__ RI2)
{
    __shared__ float At[32 * 65];
    __shared__ float Bl[32 * 64];
    const int tid = threadIdx.x;
    const int r0 = blockIdx.x * 64, c0 = blockIdx.y * 64;
    const int blk = c0 >> 7;
    const int gb = c0 & 127;
    const float* bsrc = (blk < 18) ? (rootw + (long)blk * FIN * 128) : (initw + (long)(blk - 18) * FIN * 128);
    const int tr = tid >> 4, tc = tid & 15;
    float acc[4][4] = {};
    for (int f0 = 0; f0 < FIN; f0 += 32) {
        __syncthreads();
        for (int s = tid; s < 64 * 32; s += 256) {
            const int r = s >> 5, kk = s & 31; const int f = f0 + kk;
            At[kk * 65 + r] = (f < FIN) ? xi[(long)(r0 + r) * FIN + f] : 0.f;
        }
        for (int s = tid; s < 32 * 64; s += 256) {
            const int kk = s >> 6, cc = s & 63; const int f = f0 + kk;
            Bl[s] = (f < FIN) ? bsrc[(long)f * 128 + gb + cc] : 0.f;
        }
        __syncthreads();
#pragma unroll 8
        for (int kk = 0; kk < 32; ++kk) {
            const float4 a4 = *(const float4*)&At[kk * 65 + tr * 4];
            const float4 b4 = *(const float4*)&Bl[kk * 64 + tc * 4];
            const float av[4] = {a4.x, a4.y, a4.z, a4.w};
            const float bv[4] = {b4.x, b4.y, b4.z, b4.w};
#pragma unroll
            for (int m = 0; m < 4; ++m)
#pragma unroll
                for (int n = 0; n < 4; ++n) acc[m][n] = fmaf(av[m], bv[n], acc[m][n]);
        }
    }
    float4 bq = {0.f, 0.f, 0.f, 0.f};
    if (blk < 18) bq = *(const float4*)&abias[c0 + tc * 4];
#pragma unroll
    for (int m = 0; m < 4; ++m) {
        float4 o4 = {acc[m][0] + bq.x, acc[m][1] + bq.y, acc[m][2] + bq.z, acc[m][3] + bq.w};
        *(float4*)&RI2[((size_t)blk * 1600 + (r0 + tr * 4 + m)) * 128 + gb + tc * 4] = o4;
    }
}

// ---------------- ARMA per-step MFMA: 1200 single-wave blocks, 16 rows x 32 cols each ----------------
template<int INIT>
__global__ __launch_bounds__(64) void arma_step_mfma(const float* __restrict__ Xin,
    const float* __restrict__ RI2, const ushort* __restrict__ Bh, const ushort* __restrict__ Bl,
    float* __restrict__ Xout, int t)
{
    const int rt = blockIdx.x, cg = blockIdx.y, k = blockIdx.z;
    const int l = threadIdx.x;
    const int r0 = rt * 16;

    const int ar = r0 + (l & 15);
    const int aa = ar % NA;
    const bool avalid = (aa >= 2);
    const int asrc = avalid ? (ar - 1) : ar;
    bf16x8 ah[4], al[4];
#pragma unroll
    for (int kt = 0; kt < 4; ++kt) {
        const int coff = kt * 32 + (l >> 4) * 8;
        float fv[8];
        if (INIT) {
            const float4 u0 = *(const float4*)(RI2 + ((size_t)k * 1600 + asrc) * 128 + coff);
            const float4 u1 = *(const float4*)(RI2 + ((size_t)k * 1600 + asrc) * 128 + coff + 4);
            const int psrc = (asrc >= 1) ? (asrc - 1) : 0;
            const float4 p0 = *(const float4*)(RI2 + ((size_t)(18 + k) * 1600 + psrc) * 128 + coff);
            const float4 p1 = *(const float4*)(RI2 + ((size_t)(18 + k) * 1600 + psrc) * 128 + coff + 4);
            const float pm = (aa >= 3) ? 1.f : 0.f;
            fv[0] = fmaxf(u0.x + pm * p0.x, 0.f); fv[1] = fmaxf(u0.y + pm * p0.y, 0.f);
            fv[2] = fmaxf(u0.z + pm * p0.z, 0.f); fv[3] = fmaxf(u0.w + pm * p0.w, 0.f);
            fv[4] = fmaxf(u1.x + pm * p1.x, 0.f); fv[5] = fmaxf(u1.y + pm * p1.y, 0.f);
            fv[6] = fmaxf(u1.z + pm * p1.z, 0.f); fv[7] = fmaxf(u1.w + pm * p1.w, 0.f);
        } else {
            const float4 u0 = *(const float4*)(Xin + ((size_t)k * 1600 + asrc) * 128 + coff);
            const float4 u1 = *(const float4*)(Xin + ((size_t)k * 1600 + asrc) * 128 + coff + 4);
            fv[0] = u0.x; fv[1] = u0.y; fv[2] = u0.z; fv[3] = u0.w;
            fv[4] = u1.x; fv[5] = u1.y; fv[6] = u1.z; fv[7] = u1.w;
        }
        ushort th[8], tl[8];
#pragma unroll
        for (int t8 = 0; t8 < 8; ++t8) {
            const float f = avalid ? fv[t8] : 0.f;
            th[t8] = rne_bf16(f);
            tl[t8] = rne_bf16(f - bf16_to_f32(th[t8]));
        }
        ah[kt] = *(const bf16x8*)th;
        al[kt] = *(const bf16x8*)tl;
    }

    f32x4 acc[2];
    acc[0] = (f32x4)0.f; acc[1] = (f32x4)0.f;
    const size_t wb = (size_t)(((t - 1) * 3 + k) * 32) * 512;
#pragma unroll
    for (int kt = 0; kt < 4; ++kt) {
        bf16x8 bh2[2], bl2[2];
#pragma unroll
        for (int n2 = 0; n2 < 2; ++n2) {
            const int n = cg * 2 + n2;
            const size_t fo = wb + (size_t)(n * 4 + kt) * 512 + (size_t)l * 8;
            bh2[n2] = *(const bf16x8*)(Bh + fo);
            bl2[n2] = *(const bf16x8*)(Bl + fo);
        }
#pragma unroll
        for (int n2 = 0; n2 < 2; ++n2) {
            acc[n2] = __builtin_amdgcn_mfma_f32_16x16x32_bf16(ah[kt], bh2[n2], acc[n2], 0, 0, 0);
            acc[n2] = __builtin_amdgcn_mfma_f32_16x16x32_bf16(ah[kt], bl2[n2], acc[n2], 0, 0, 0);
            acc[n2] = __builtin_amdgcn_mfma_f32_16x16x32_bf16(al[kt], bh2[n2], acc[n2], 0, 0, 0);
        }
    }

    const float* rroot = RI2 + (size_t)(t * 3 + k) * 1600 * 128;
#pragma unroll
    for (int n2 = 0; n2 < 2; ++n2) {
        const int col = (cg * 2 + n2) * 16 + (l & 15);
#pragma unroll
        for (int r = 0; r < 4; ++r) {
            const int crow = r0 + (l >> 4) * 4 + r;
            const float rv = rroot[(size_t)crow * 128 + col];
            Xout[((size_t)k * 1600 + crow) * 128 + col] = fmaxf(acc[n2][r] + rv, 0.f);
        }
    }
}

// ---------------- final: mean over k-banks + relu, aa-attention, MLP ----------------
__global__ __launch_bounds__(256) void final_k(const float* __restrict__ G,
    const float* __restrict__ waa, const float* __restrict__ baa,
    const float* __restrict__ w1, const float* __restrict__ b1,
    const float* __restrict__ w2, const float* __restrict__ b2,
    const float* __restrict__ w3, const float* __restrict__ b3,
    const float* __restrict__ w4, const float* __restrict__ b4, float* __restrict__ out)
{
    __shared__ float gl[50 * 129];
    __shared__ float sc[64];
    __shared__ float pl[128];
    __shared__ float h1l[64], h2l[32], h3l[16];
    __shared__ float wl[128];
    const int b = blockIdx.x, tid = threadIdx.x;
    for (int s = tid; s < 50 * 128; s += 256) {
        const int a = s >> 7, o = s & 127;
        const size_t r = ((size_t)b * 50 + a) * 128 + o;
        const float v = (G[r] + G[(size_t)1600 * 128 + r] + G[(size_t)2 * 1600 * 128 + r]) * (1.f / 3.f);
        gl[a * 129 + o] = fmaxf(v, 0.f);
    }
    if (tid < 128) wl[tid] = waa[tid];
    __syncthreads();
    if (tid < 50) {
        float acc = baa[0];
        for (int f = 0; f < 128; ++f) acc = fmaf(gl[tid * 129 + f], wl[f], acc);
        sc[tid] = acc;
    }
    __syncthreads();
    if (tid < 64) {
        const float v = (tid < 50) ? sc[tid] : -1e30f;
        float m = v;
        for (int d = 32; d; d >>= 1) m = fmaxf(m, __shfl_xor(m, d));
        const float e = (tid < 50) ? expf(v - m) : 0.f;
        float ssum = e;
        for (int d = 32; d; d >>= 1) ssum += __shfl_xor(ssum, d);
        if (tid < 50) sc[tid] = e / ssum;
    }
    __syncthreads();
    if (tid < 128) {
        float acc = 0.f;
        for (int a = 0; a < 50; ++a) acc = fmaf(sc[a], gl[a * 129 + tid], acc);
        pl[tid] = acc;
    }
    __syncthreads();
    if (tid < 64) {
        float acc = b1[tid];
        for (int f = 0; f < 128; ++f) acc = fmaf(pl[f], w1[f * 64 + tid], acc);
        h1l[tid] = fmaxf(acc, 0.f);
    }
    __syncthreads();
    if (tid < 32) {
        float acc = b2[tid];
        for (int f = 0; f < 64; ++f) acc = fmaf(h1l[f], w2[f * 32 + tid], acc);
        h2l[tid] = fmaxf(acc, 0.f);
    }
    __syncthreads();
    if (tid < 16) {
        float acc = b3[tid];
        for (int f = 0; f < 32; ++f) acc = fmaf(h2l[f], w3[f * 16 + tid], acc);
        h3l[tid] = fmaxf(acc, 0.f);
    }
    __syncthreads();
    if (tid == 0) {
        float acc = b4[0];
        for (int f = 0; f < 16; ++f) acc = fmaf(h3l[f], w4[f], acc);
        out[b] = acc;
    }
}

extern "C" void kernel_launch(void* const* d_in, const int* in_sizes, int n_in,
                              void* d_out, int out_size, void* d_ws, size_t ws_size,
                              hipStream_t stream) {
    const float* x     = (const float*)d_in[0];
    const int*   eidx  = (const int*)d_in[1];
    const float* ea    = (const float*)d_in[2];
    const float* aaf   = (const float*)d_in[4];
    const float* we1   = (const float*)d_in[5];
    const float* be1   = (const float*)d_in[6];
    const float* root1 = (const float*)d_in[7];
    const float* bias1 = (const float*)d_in[8];
    const float* we2   = (const float*)d_in[9];
    const float* be2   = (const float*)d_in[10];
    const float* root2 = (const float*)d_in[11];
    const float* bias2 = (const float*)d_in[12];
    const float* waw   = (const float*)d_in[13];
    const float* wab   = (const float*)d_in[14];
    const float* initw = (const float*)d_in[15];
    const float* armaw = (const float*)d_in[16];
    const float* rootw = (const float*)d_in[17];
    const float* abias = (const float*)d_in[18];
    const float* waa   = (const float*)d_in[19];
    const float* baa   = (const float*)d_in[20];
    const float* w1    = (const float*)d_in[21];
    const float* b1    = (const float*)d_in[22];
    const float* w2    = (const float*)d_in[23];
    const float* b2    = (const float*)d_in[24];
    const float* w3    = (const float*)d_in[25];
    const float* b3    = (const float*)d_in[26];
    const float* w4    = (const float*)d_in[27];
    const float* b4    = (const float*)d_in[28];
    float* out = (float*)d_out;

    const int* src = eidx;
    const int* dst = eidx + N_EDGES;

    char* ws = (char*)d_ws;
    size_t off = 0;
    float* h1     = (float*)(ws + off); off += (size_t)N_NODES * 64 * 4;
    float* h2     = (float*)(ws + off); off += (size_t)N_NODES * 64 * 4;
    float* scores = (float*)(ws + off); off += (size_t)N_NODES * 4;
    float* attn   = (float*)(ws + off); off += (size_t)N_NODES * 4;
    float* xi     = (float*)(ws + off); off += (size_t)1600 * FIN * 4;
    float* RI2    = (float*)(ws + off); off += (size_t)NBANKS * 1600 * 128 * 4;
    float* XA     = (float*)(ws + off); off += (size_t)3 * 1600 * 128 * 4;
    float* XB     = (float*)(ws + off); off += (size_t)3 * 1600 * 128 * 4;
    float* G      = (float*)(ws + off); off += (size_t)3 * 1600 * 128 * 4;
    ushort* wt1h  = (ushort*)(ws + off); off += (size_t)17 * 8 * 64 * 8 * 2;
    ushort* wt1l  = (ushort*)(ws + off); off += (size_t)17 * 8 * 64 * 8 * 2;
    ushort* wt2h  = (ushort*)(ws + off); off += (size_t)17 * 8 * 64 * 8 * 2;
    ushort* wt2l  = (ushort*)(ws + off); off += (size_t)17 * 8 * 64 * 8 * 2;
    ushort* abh   = (ushort*)(ws + off); off += (size_t)15 * 32 * 64 * 8 * 2;
    ushort* abl   = (ushort*)(ws + off); off += (size_t)15 * 32 * 64 * 8 * 2;

    prep_all<<<188, 256, 0, stream>>>(we1, be1, we2, be2, armaw, wt1h, wt1l, wt2h, wt2l, abh, abl);

    // conv1 (relu deferred to consumers)
    root_gemm<0><<<N_NODES / 64, 256, 0, stream>>>(x, root1, bias1, h1);
    edge_conv_mfma<0><<<N_EDGES / TE, 256, 0, stream>>>(x, ea, src, dst, wt1h, wt1l, h1);
    // conv2 (reads relu(h1) on load)
    root_gemm<1><<<N_NODES / 64, 256, 0, stream>>>(h1, root2, bias2, h2);
    edge_conv_mfma<1><<<N_EDGES / TE, 256, 0, stream>>>(h1, ea, src, dst, wt2h, wt2l, h2);
    // attention pooling -> xi
    scores_k<<<(N_NODES + 255) / 256, 256, 0, stream>>>(h2, waw, wab, scores);
    softmax_k<<<NB, 256, 0, stream>>>(scores, attn);
    amino_k<<<1600 / 4, 256, 0, stream>>>(h2, attn, aaf, xi);
    // ARMA: RI2 banks, then 5 wide per-step dispatches (t=5 writes G)
    ri_gemm<<<dim3(25, 42), 256, 0, stream>>>(xi, rootw, initw, abias, RI2);
    const dim3 agrid(100, 4, 3);
    arma_step_mfma<1><<<agrid, 64, 0, stream>>>(XB, RI2, abh, abl, XA, 1);
    arma_step_mfma<0><<<agrid, 64, 0, stream>>>(XA, RI2, abh, abl, XB, 2);
    arma_step_mfma<0><<<agrid, 64, 0, stream>>>(XB, RI2, abh, abl, XA, 3);
    arma_step_mfma<0><<<agrid, 64, 0, stream>>>(XA, RI2, abh, abl, XB, 4);
    arma_step_mfma<0><<<agrid, 64, 0, stream>>>(XB, RI2, abh, abl, G, 5);
    // readout + MLP
    final_k<<<NB, 256, 0, stream>>>(G, waa, baa, w1, b1, w2, b2, w3, b3, w4, b4, out);
}